// Round 7
// baseline (216.867 us; speedup 1.0000x reference)
//
#include <hip/hip_runtime.h>
#include <hip/hip_bf16.h>

#define OBS_LEN 16
#define PRED_LEN 25
#define NNODES 192
#define PAIRS 36864          // 192*192
#define ENC 64
#define EMB 32
#define DEC 128
#define SOCDYN 176           // 144 + 32
#define PAIR_GROUPS 2304     // 36864/16 worst case
#define EGO_GROUPS 12        // 192/16
#define HSTR 136             // dec hist row stride in shorts
#define LOG2E 1.4426950408889634f

typedef short short8 __attribute__((ext_vector_type(8)));
typedef float f32x4 __attribute__((ext_vector_type(4)));

// minimal-sequence activations: v_mul/v_fma + v_exp + v_add + v_rcp
__device__ __forceinline__ float sigm(float x) {
    return __builtin_amdgcn_rcpf(1.f + __builtin_amdgcn_exp2f(-LOG2E * x));
}
__device__ __forceinline__ float tanh_f(float x) {
    return fmaf(-2.f, __builtin_amdgcn_rcpf(1.f + __builtin_amdgcn_exp2f((2.f * LOG2E) * x)), 1.f);
}
__device__ __forceinline__ float expf_fast(float x) {
    return __builtin_amdgcn_exp2f(LOG2E * x);
}
__device__ __forceinline__ float lrelu(float x) { return (x >= 0.f) ? x : 0.1f * x; }

__device__ __forceinline__ unsigned short f2bf(float f) {
    union { float f; unsigned u; } v; v.f = f;
    unsigned r = v.u + 0x7fffu + ((v.u >> 16) & 1u);   // RNE
    return (unsigned short)(r >> 16);
}
__device__ __forceinline__ float bf2f(unsigned short s) {
    union { unsigned u; float f; } v; v.u = ((unsigned)s) << 16; return v.f;
}

// ---------------------------------------------------------------------------
// Dedup of masks_idxs: LDS bitmap -> compacted ascending unique-row list +
// count. Single block (all weight-prep transposes were identity layouts and
// are now converted inline in the consumers).
// ---------------------------------------------------------------------------
__global__ __launch_bounds__(1024, 1)
void dedup_kernel(const int* __restrict__ masks_idxs,
                  int* __restrict__ list, int* __restrict__ list_count)
{
    __shared__ unsigned bm[1152];       // 36864 bits
    __shared__ int pcs[1024];
    const int t = threadIdx.x;
    for (int i = t; i < 1152; i += 1024) bm[i] = 0u;
    __syncthreads();
    for (int i = t; i < 12288; i += 1024) {
        const int r = masks_idxs[i];
        atomicOr(&bm[r >> 5], 1u << (r & 31));
    }
    __syncthreads();
    int pc = 0;
    if (t < 576) pc = __popc(bm[2 * t]) + __popc(bm[2 * t + 1]);
    pcs[t] = pc;
    __syncthreads();
    for (int ofs = 1; ofs < 1024; ofs <<= 1) {
        int v = (t >= ofs) ? pcs[t - ofs] : 0;
        __syncthreads();
        pcs[t] += v;
        __syncthreads();
    }
    if (t == 1023) list_count[0] = pcs[1023];
    if (t < 576) {
        int base = pcs[t] - pc;   // exclusive prefix
#pragma unroll
        for (int wi = 0; wi < 2; ++wi) {
            unsigned wv = bm[2 * t + wi];
            const int rowbase = (2 * t + wi) * 32;
            while (wv) {
                const int bit = __ffs(wv) - 1;
                list[base++] = rowbase + bit;
                wv &= wv - 1;
            }
        }
    }
}

// ---------------------------------------------------------------------------
// Encoder LSTM, BARRIER-FREE: one 64-lane wave per block owns 16 rows for all
// 16 steps. All 48 weight A-frags (4g x 4jt x 3kc) register-resident; h is
// transposed C-layout -> B-layout through a per-block LDS scratch hw[16][72]
// within the wave (lgkmcnt ordering only — zero s_barrier in the kernel).
// ---------------------------------------------------------------------------
__global__ __launch_bounds__(64, 1)
void enc_lstm_kernel(const float* __restrict__ obs_traj,   // [16,192,2]
                     const float* __restrict__ obs_ngbrs,  // [16,36864,2]
                     const float* __restrict__ Wip, const float* __restrict__ bip,
                     const float* __restrict__ Wih_e,      // [256,32]
                     const float* __restrict__ Whh_e,      // [256,64]
                     const float* __restrict__ bih, const float* __restrict__ bhh,
                     const int* __restrict__ list, const int* __restrict__ list_count,
                     float* __restrict__ Hn,               // [36864,64] fp32 (sparse rows)
                     float* __restrict__ final_h)          // [192,64] fp32
{
    __shared__ __align__(16) short hw[16 * 72];        // h[n][k], stride 72 shorts
    __shared__ __align__(16) float xs[OBS_LEN][16][2]; // staged inputs

    const int lane = threadIdx.x;
    const int ln = lane & 15, kq = lane >> 4;
    const int b = blockIdx.x;
    const bool is_ego = (b >= PAIR_GROUPS);
    int cnt = 0;
    if (!is_ego) {
        cnt = list_count[0];
        if (b * 16 >= cnt) return;                     // uniform exit (1 wave)
    }
    const int myrow = is_ego ? ((b - PAIR_GROUPS) * 16 + ln)
                             : list[min(b * 16 + ln, cnt - 1)];

    // stage x: lane (kq,ln) loads steps kq*4..kq*4+3 of row ln
    {
        const float* sp = is_ego ? obs_traj : obs_ngbrs;
        const int stride = is_ego ? (NNODES * 2) : (PAIRS * 2);
#pragma unroll
        for (int i = 0; i < 4; ++i) {
            const int s = kq * 4 + i;
            const float* p = sp + (long)s * stride + (long)myrow * 2;
            xs[s][ln][0] = p[0];
            xs[s][ln][1] = p[1];
        }
    }

    // input-embedding weights for this lane's k-slice (k = kq*8 + jj)
    float w0[8], w1[8], bb[8];
#pragma unroll
    for (int jj = 0; jj < 8; ++jj) {
        const int k = kq * 8 + jj;
        w0[jj] = Wip[2 * k];
        w1[jj] = Wip[2 * k + 1];
        bb[jj] = bip[k];
    }

    // weight A-frags + bias (inline fp32->bf16; identity layout)
    short8 af[4][4][3];
    float bsv[4][4][4];
#pragma unroll
    for (int g = 0; g < 4; ++g)
#pragma unroll
        for (int jt = 0; jt < 4; ++jt) {
            const int m = g * 64 + jt * 16 + ln;
#pragma unroll
            for (int kc = 0; kc < 3; ++kc) {
                const float* wp = (kc == 0) ? (Wih_e + m * 32 + kq * 8)
                                            : (Whh_e + m * 64 + (kc - 1) * 32 + kq * 8);
                short8 a;
#pragma unroll
                for (int j = 0; j < 8; ++j) a[j] = (short)f2bf(wp[j]);
                af[g][jt][kc] = a;
            }
            const int mb = g * 64 + jt * 16 + kq * 4;
#pragma unroll
            for (int r = 0; r < 4; ++r) bsv[g][jt][r] = bih[mb + r] + bhh[mb + r];
        }

    float cst[4][4];
#pragma unroll
    for (int jt = 0; jt < 4; ++jt)
#pragma unroll
        for (int r = 0; r < 4; ++r) cst[jt][r] = 0.f;

    short8 hf1, hf2;
#pragma unroll
    for (int j = 0; j < 8; ++j) { hf1[j] = 0; hf2[j] = 0; }

    for (int s = 0; s < OBS_LEN; ++s) {
        const float x0 = xs[s][ln][0], x1 = xs[s][ln][1];
        short8 be;
#pragma unroll
        for (int jj = 0; jj < 8; ++jj) {
            const float e = lrelu(fmaf(x0, w0[jj], fmaf(x1, w1[jj], bb[jj])));
            be[jj] = (short)f2bf(e);
        }
#pragma unroll
        for (int jt = 0; jt < 4; ++jt) {
            f32x4 acc[4];
#pragma unroll
            for (int g = 0; g < 4; ++g) {
                f32x4 a = { bsv[g][jt][0], bsv[g][jt][1], bsv[g][jt][2], bsv[g][jt][3] };
                a = __builtin_amdgcn_mfma_f32_16x16x32_bf16(af[g][jt][0], be, a, 0, 0, 0);
                a = __builtin_amdgcn_mfma_f32_16x16x32_bf16(af[g][jt][1], hf1, a, 0, 0, 0);
                acc[g] = __builtin_amdgcn_mfma_f32_16x16x32_bf16(af[g][jt][2], hf2, a, 0, 0, 0);
            }
            unsigned long long pk = 0;
#pragma unroll
            for (int r = 0; r < 4; ++r) {
                const float cn = fmaf(sigm(acc[1][r]), cst[jt][r],
                                      sigm(acc[0][r]) * tanh_f(acc[2][r]));
                cst[jt][r] = cn;
                const float h = sigm(acc[3][r]) * tanh_f(cn);
                pk |= (unsigned long long)f2bf(h) << (16 * r);
            }
            // h for (n=ln, j = jt*16 + kq*4 + r) -> hw[n][j]
            *(unsigned long long*)&hw[ln * 72 + jt * 16 + kq * 4] = pk;
        }
        // in-wave transpose readback (compiler inserts lgkmcnt wait)
        hf1 = *(const short8*)&hw[ln * 72 + kq * 8];
        hf2 = *(const short8*)&hw[ln * 72 + 32 + kq * 8];
    }

    // final h -> global fp32: lane covers (row rr, k = q*16..q*16+15)
    {
        const int rr = lane >> 2, q = lane & 3;
        const int row2 = is_ego ? ((b - PAIR_GROUPS) * 16 + rr)
                                : list[min(b * 16 + rr, cnt - 1)];
        float* dst = is_ego ? (final_h + (long)row2 * 64 + q * 16)
                            : (Hn + (long)row2 * 64 + q * 16);
        const short8 ha = *(const short8*)&hw[rr * 72 + q * 16];
        const short8 hb2 = *(const short8*)&hw[rr * 72 + q * 16 + 8];
        float vals[16];
#pragma unroll
        for (int j = 0; j < 8; ++j) {
            vals[j] = bf2f((unsigned short)ha[j]);
            vals[8 + j] = bf2f((unsigned short)hb2[j]);
        }
#pragma unroll
        for (int j = 0; j < 4; ++j) {
            float4 vv = { vals[4 * j], vals[4 * j + 1], vals[4 * j + 2], vals[4 * j + 3] };
            *(float4*)(dst + 4 * j) = vv;
        }
    }
}

// ---------------------------------------------------------------------------
// conv via MFMA (R6 structure; weights converted inline from fp32 — the
// [o][c*9+tap] layout is an identity reshape of Wc1/Wc2).
// ---------------------------------------------------------------------------
__global__ __launch_bounds__(256, 1)
void conv_kernel(const float* __restrict__ Hn, const int* __restrict__ masks_idxs,
                 const float* __restrict__ final_h, const float* __restrict__ Wdyn,
                 const float* __restrict__ bdyn,
                 const float* __restrict__ Wc1, const float* __restrict__ bc1,
                 const float* __restrict__ Wc2, const float* __restrict__ bc2,
                 float* __restrict__ enc)
{
    __shared__ __align__(16) short in2bf[64][72];   //  [c][p], p=u*8+v
    __shared__ __align__(16) short imc1[48][584];   //  [n][k]
    __shared__ __align__(16) short s1bf[64][40];    //  [c][x*6+y]
    __shared__ __align__(16) short imc2[16][584];   //  [n2][k]
    __shared__ __align__(16) float red[4][256];
    __shared__ float s2s[16 * 17];

    const int t = threadIdx.x, b = blockIdx.x;
    const int w = t >> 6, lane = t & 63, ln = lane & 15, kq = lane >> 4;

    // conv1 A-frags: m = w*16 + ln, 18 K-chunks (fp32 loads + inline cvt)
    short8 a1f[18];
#pragma unroll
    for (int kc = 0; kc < 18; ++kc) {
        const float* wp = Wc1 + (w * 16 + ln) * 576 + kc * 32 + kq * 8;
        short8 a;
#pragma unroll
        for (int j = 0; j < 8; ++j) a[j] = (short)f2bf(wp[j]);
        a1f[kc] = a;
    }

    // conv2 A-frags: m = ln; wave w owns K-chunks [c2start, c2start+c2cnt)
    const int c2start = (w < 2) ? w * 5 : 10 + (w - 2) * 4;
    const int c2cnt = (w < 2) ? 5 : 4;
    short8 a2f[5];
#pragma unroll
    for (int i = 0; i < 5; ++i) {
        const int kc = c2start + min(i, c2cnt - 1);
        const float* wp = Wc2 + ln * 576 + kc * 32 + kq * 8;
        short8 a;
#pragma unroll
        for (int j = 0; j < 8; ++j) a[j] = (short)f2bf(wp[j]);
        a2f[i] = a;
    }

    // gather social grid (bf16, lossless: h was bf16-rounded in the encoder)
    for (int i = 0; i < 16; ++i) {
        const int c = t & 63;
        const int p = (i << 2) + (t >> 6);      // p = u*8 + v
        const int u = p >> 3, v = p & 7;
        const int row = masks_idxs[b * 64 + v * 8 + u];
        in2bf[c][p] = (short)f2bf(Hn[(long)row * 64 + c]);
    }
    // traj_enc
    if (t < 32) {
        float acc = bdyn[t];
        for (int k = 0; k < 64; ++k) acc = fmaf(final_h[b * 64 + k], Wdyn[t * 64 + k], acc);
        enc[b * SOCDYN + t] = lrelu(acc);
    }
    __syncthreads();

    // im2col for conv1: n = x*6+y < 36
    for (int i = t; i < 36 * 64; i += 256) {
        const int n = i >> 6, c = i & 63;
        const int x = n / 6, y = n % 6;
        short* dst = &imc1[n][c * 9];
#pragma unroll
        for (int dx = 0; dx < 3; ++dx)
#pragma unroll
            for (int dy = 0; dy < 3; ++dy)
                dst[dx * 3 + dy] = in2bf[c][(x + dx) * 8 + (y + dy)];
    }
    __syncthreads();

    // conv1 MFMA: wave w -> o in [16w,16w+16), 3 N-tiles x 18 K-chunks
    {
        float bcv[4];
#pragma unroll
        for (int r = 0; r < 4; ++r) bcv[r] = bc1[w * 16 + kq * 4 + r];
#pragma unroll
        for (int nt = 0; nt < 3; ++nt) {
            f32x4 acc = { bcv[0], bcv[1], bcv[2], bcv[3] };
            const short* bp = &imc1[nt * 16 + ln][kq * 8];
#pragma unroll
            for (int kc = 0; kc < 18; ++kc) {
                const short8 bfr = *(const short8*)(bp + kc * 32);
                acc = __builtin_amdgcn_mfma_f32_16x16x32_bf16(a1f[kc], bfr, acc, 0, 0, 0);
            }
            const int n = nt * 16 + ln;
            if (n < 36) {
#pragma unroll
                for (int r = 0; r < 4; ++r)
                    s1bf[w * 16 + kq * 4 + r][n] = (short)f2bf(lrelu(acc[r]));
            }
        }
    }
    __syncthreads();

    // im2col for conv2: n2 = x*4+y
    for (int i = t; i < 16 * 64; i += 256) {
        const int n2 = i >> 6, c = i & 63;
        const int x = n2 >> 2, y = n2 & 3;
        short* dst = &imc2[n2][c * 9];
#pragma unroll
        for (int dx = 0; dx < 3; ++dx)
#pragma unroll
            for (int dy = 0; dy < 3; ++dy)
                dst[dx * 3 + dy] = s1bf[c][(x + dx) * 6 + (y + dy)];
    }
    __syncthreads();

    // conv2 MFMA: K-split partials
    {
        f32x4 acc = { 0.f, 0.f, 0.f, 0.f };
        const short* bp = &imc2[ln][kq * 8];
#pragma unroll
        for (int i = 0; i < 5; ++i) {
            if (i < c2cnt) {
                const short8 bfr = *(const short8*)(bp + (c2start + i) * 32);
                acc = __builtin_amdgcn_mfma_f32_16x16x32_bf16(a2f[i], bfr, acc, 0, 0, 0);
            }
        }
        *(f32x4*)&red[w][lane * 4] = acc;
    }
    __syncthreads();

    // reduce partials + bias + lrelu -> s2s[m][n2]
    {
        const float v = red[0][t] + red[1][t] + red[2][t] + red[3][t];
        const int l = t >> 2, r = t & 3;
        const int m = (l >> 4) * 4 + r, n = l & 15;
        s2s[m * 17 + n] = lrelu(v + bc2[m]);
    }
    __syncthreads();

    // maxpool 2x2 stride 1 -> enc[32..175]
    if (t < 144) {
        const int o = t / 9, ij = t % 9, i = ij / 3, j = ij % 3;
        const float v00 = s2s[o * 17 + i * 4 + j];
        const float v01 = s2s[o * 17 + i * 4 + j + 1];
        const float v10 = s2s[o * 17 + (i + 1) * 4 + j];
        const float v11 = s2s[o * 17 + (i + 1) * 4 + j + 1];
        enc[b * SOCDYN + 32 + t] = fmaxf(fmaxf(v00, v01), fmaxf(v10, v11));
    }
}

// ---------------------------------------------------------------------------
// Decoder LSTM via MFMA (R6 LDS-hist structure; weights inline from fp32,
// exp2-based activations).
// ---------------------------------------------------------------------------
__global__ __launch_bounds__(512, 1)
void dec_kernel(const float* __restrict__ enc,                // [192,176] fp32
                const float* __restrict__ Wih_d,              // [512,176] fp32
                const float* __restrict__ Whh_d,              // [512,128] fp32
                const float* __restrict__ bih_d, const float* __restrict__ bhh_d,
                const float* __restrict__ Wop, const float* __restrict__ bop,
                float* __restrict__ out)                      // [25,192,5]
{
    __shared__ __align__(16) short encfr[3072];
    __shared__ __align__(16) short hist[PRED_LEN * 16 * HSTR]; // 108800 B
    __shared__ float wop_s[5 * 128];

    const int t = threadIdx.x;
    const int w = t >> 6, lane = t & 63, ln = lane & 15, kq = lane >> 4;
    const int row0 = blockIdx.x * 16;

    for (int i = t; i < 3072; i += 512) {
        const int n = i / 192, k = i % 192;
        const float v = (k < 176) ? enc[(row0 + n) * SOCDYN + k] : 0.f;
        encfr[(k >> 3) * 128 + n * 8 + (k & 7)] = (short)f2bf(v);
    }
    for (int i = t; i < 640; i += 512) wop_s[i] = Wop[i];

    // persistent Whh A-frags (inline fp32->bf16)
    short8 wfrag[4][4];
#pragma unroll
    for (int g = 0; g < 4; ++g)
#pragma unroll
        for (int kc = 0; kc < 4; ++kc) {
            const float* wp = Whh_d + (g * 128 + w * 16 + ln) * 128 + kc * 32 + kq * 8;
            short8 a;
#pragma unroll
            for (int j = 0; j < 8; ++j) a[j] = (short)f2bf(wp[j]);
            wfrag[g][kc] = a;
        }

    f32x4 zin[4];
#pragma unroll
    for (int g = 0; g < 4; ++g)
#pragma unroll
        for (int r = 0; r < 4; ++r) {
            const int m = g * 128 + w * 16 + kq * 4 + r;
            zin[g][r] = bih_d[m] + bhh_d[m];
        }

    __syncthreads();

    // zin += Wih_d @ enc^T (K padded 176->192; OOB chunks are zero frags)
#pragma unroll
    for (int kc = 0; kc < 6; ++kc) {
        const short8 bfr = *(const short8*)&encfr[(kc * 4 + kq) * 128 + ln * 8];
        const int kk = kc * 32 + kq * 8;
#pragma unroll
        for (int g = 0; g < 4; ++g) {
            short8 afr;
            if (kk < 176) {
                const float* wp = Wih_d + (g * 128 + w * 16 + ln) * 176 + kk;
#pragma unroll
                for (int j = 0; j < 8; ++j) afr[j] = (short)f2bf(wp[j]);
            } else {
#pragma unroll
                for (int j = 0; j < 8; ++j) afr[j] = 0;
            }
            zin[g] = __builtin_amdgcn_mfma_f32_16x16x32_bf16(afr, bfr, zin[g], 0, 0, 0);
        }
    }

    float c4[4] = {0.f, 0.f, 0.f, 0.f};
    const int hb_wr = ln * HSTR + w * 16 + kq * 4;

    for (int stp = 0; stp < PRED_LEN; ++stp) {
        f32x4 z[4];
#pragma unroll
        for (int g = 0; g < 4; ++g) z[g] = zin[g];
        if (stp > 0) {
            const short* hp = &hist[(stp - 1) * 16 * HSTR + ln * HSTR + kq * 8];
            short8 bh[4];
#pragma unroll
            for (int kc = 0; kc < 4; ++kc)
                bh[kc] = *(const short8*)(hp + kc * 32);
#pragma unroll
            for (int kc = 0; kc < 4; ++kc)
#pragma unroll
                for (int g = 0; g < 4; ++g)
                    z[g] = __builtin_amdgcn_mfma_f32_16x16x32_bf16(wfrag[g][kc], bh[kc], z[g], 0, 0, 0);
        }
        unsigned long long pk = 0;
#pragma unroll
        for (int r = 0; r < 4; ++r) {
            const float cn = fmaf(sigm(z[1][r]), c4[r], sigm(z[0][r]) * tanh_f(z[2][r]));
            c4[r] = cn;
            const float h = sigm(z[3][r]) * tanh_f(cn);
            pk |= (unsigned long long)f2bf(h) << (16 * r);
        }
        *(unsigned long long*)&hist[stp * 16 * HSTR + hb_wr] = pk;
        __syncthreads();   // hist[stp] visible for next step
    }

    // epilogue: out = hs @ Wop.T (+ exp/exp/tanh), hs from LDS
    for (int pi = t; pi < PRED_LEN * 16; pi += 512) {
        const int ts = pi >> 4, n = pi & 15;
        const short* hp = &hist[(ts * 16 + n) * HSTR];
        float a0 = bop[0], a1 = bop[1], a2 = bop[2], a3 = bop[3], a4 = bop[4];
#pragma unroll 4
        for (int kb = 0; kb < 16; ++kb) {
            const short8 h8 = *(const short8*)(hp + kb * 8);
#pragma unroll
            for (int q = 0; q < 8; ++q) {
                const float h = bf2f((unsigned short)h8[q]);
                const int k = kb * 8 + q;
                a0 = fmaf(h, wop_s[0 * 128 + k], a0);
                a1 = fmaf(h, wop_s[1 * 128 + k], a1);
                a2 = fmaf(h, wop_s[2 * 128 + k], a2);
                a3 = fmaf(h, wop_s[3 * 128 + k], a3);
                a4 = fmaf(h, wop_s[4 * 128 + k], a4);
            }
        }
        float* op = &out[((long)ts * NNODES + row0 + n) * 5];
        op[0] = a0;
        op[1] = a1;
        op[2] = expf_fast(a2);
        op[3] = expf_fast(a3);
        op[4] = tanh_f(a4);
    }
}

// ---------------------------------------------------------------------------
extern "C" void kernel_launch(void* const* d_in, const int* in_sizes, int n_in,
                              void* d_out, int out_size, void* d_ws, size_t ws_size,
                              hipStream_t stream) {
    const float* obs_traj   = (const float*)d_in[0];
    const float* obs_ngbrs  = (const float*)d_in[1];
    const int*   masks_idxs = (const int*)d_in[3];
    const float* Wip   = (const float*)d_in[7];
    const float* bip   = (const float*)d_in[8];
    const float* Wih_e = (const float*)d_in[9];
    const float* Whh_e = (const float*)d_in[10];
    const float* bih_e = (const float*)d_in[11];
    const float* bhh_e = (const float*)d_in[12];
    const float* Wdyn  = (const float*)d_in[13];
    const float* bdyn  = (const float*)d_in[14];
    const float* Wc1   = (const float*)d_in[15];
    const float* bc1   = (const float*)d_in[16];
    const float* Wc2   = (const float*)d_in[17];
    const float* bc2   = (const float*)d_in[18];
    const float* Wih_d = (const float*)d_in[19];
    const float* Whh_d = (const float*)d_in[20];
    const float* bih_d = (const float*)d_in[21];
    const float* bhh_d = (const float*)d_in[22];
    const float* Wop   = (const float*)d_in[23];
    const float* bop   = (const float*)d_in[24];
    float* out = (float*)d_out;

    float* ws = (float*)d_ws;
    float* Hn      = ws;                       // 2359296 f
    float* final_h = Hn + 2359296;             // 12288 f
    float* encb    = final_h + 12288;          // 33792 f
    int*   list    = (int*)(encb + 33792);     // 36864 i32
    int*   list_count = list + 36864;          // 1 i32

    hipLaunchKernelGGL(dedup_kernel, dim3(1), dim3(1024), 0, stream,
                       masks_idxs, list, list_count);
    hipLaunchKernelGGL(enc_lstm_kernel, dim3(PAIR_GROUPS + EGO_GROUPS), dim3(64), 0, stream,
                       obs_traj, obs_ngbrs, Wip, bip, Wih_e, Whh_e, bih_e, bhh_e,
                       list, list_count, Hn, final_h);
    hipLaunchKernelGGL(conv_kernel, dim3(NNODES), dim3(256), 0, stream,
                       Hn, masks_idxs, final_h, Wdyn, bdyn, Wc1, bc1, Wc2, bc2, encb);
    hipLaunchKernelGGL(dec_kernel, dim3(NNODES / 16), dim3(512), 0, stream,
                       encb, Wih_d, Whh_d, bih_d, bhh_d, Wop, bop, out);
}

// Round 8
// 190.319 us; speedup vs baseline: 1.1395x; 1.1395x over previous
//
#include <hip/hip_runtime.h>
#include <hip/hip_bf16.h>

#define OBS_LEN 16
#define PRED_LEN 25
#define NNODES 192
#define PAIRS 36864          // 192*192
#define ENC 64
#define EMB 32
#define DEC 128
#define SOCDYN 176           // 144 + 32
#define PAIR_GROUPS 2304     // 36864/16 worst case
#define EGO_GROUPS 12        // 192/16
#define PREP_ELEMS 234496    // 65536+98304+36864+9216+24576
#define HSTR 136             // dec hist row stride in shorts
#define LOG2E 1.4426950408889634f

typedef short short8 __attribute__((ext_vector_type(8)));
typedef float f32x4 __attribute__((ext_vector_type(4)));

__device__ __forceinline__ float sigm(float x) {
    return __builtin_amdgcn_rcpf(1.f + __builtin_amdgcn_exp2f(-LOG2E * x));
}
__device__ __forceinline__ float tanh_f(float x) {
    return fmaf(-2.f, __builtin_amdgcn_rcpf(1.f + __builtin_amdgcn_exp2f((2.f * LOG2E) * x)), 1.f);
}
__device__ __forceinline__ float expf_fast(float x) {
    return __builtin_amdgcn_exp2f(LOG2E * x);
}
__device__ __forceinline__ float lrelu(float x) { return (x >= 0.f) ? x : 0.1f * x; }

__device__ __forceinline__ unsigned short f2bf(float f) {
    union { float f; unsigned u; } v; v.f = f;
    unsigned r = v.u + 0x7fffu + ((v.u >> 16) & 1u);   // RNE
    return (unsigned short)(r >> 16);
}
__device__ __forceinline__ float bf2f(unsigned short s) {
    union { unsigned u; float f; } v; v.u = ((unsigned)s) << 16; return v.f;
}

// ---------------------------------------------------------------------------
// Kernel 1: prep (blocks 0..228) + dedup of masks_idxs (block 229).
//  Whh_bf [512][128] bf16            (decoder recurrent)
//  Wih_bf [512][192] bf16 K-padded   (decoder input proj)
//  WT1bf  [9 tap][64 o][64 c] bf16   (conv1, tap-major for direct-B conv)
//  WT2bf  [9 tap][16 o][64 c] bf16   (conv2)
//  Wenc_bf[256][96] bf16             (encoder [Wih|Whh] fused)
// ---------------------------------------------------------------------------
__global__ __launch_bounds__(1024, 1)
void prep_dedup_kernel(const float* __restrict__ Wih_d, const float* __restrict__ Whh_d,
                       const float* __restrict__ Wc1, const float* __restrict__ Wc2,
                       const float* __restrict__ Wih_e, const float* __restrict__ Whh_e,
                       const int* __restrict__ masks_idxs,
                       unsigned short* __restrict__ Whh_bf, unsigned short* __restrict__ Wih_bf,
                       unsigned short* __restrict__ WT1bf, unsigned short* __restrict__ WT2bf,
                       unsigned short* __restrict__ Wenc_bf,
                       int* __restrict__ list, int* __restrict__ list_count)
{
    const int t = threadIdx.x, b = blockIdx.x;
    if (b < 229) {
        int idx = b * 1024 + t;
        if (idx < 65536) {
            int m = idx >> 7, k = idx & 127;
            Whh_bf[idx] = f2bf(Whh_d[m * 128 + k]);
        } else if (idx < 65536 + 98304) {
            int i = idx - 65536;
            int m = i / 192, k = i % 192;
            Wih_bf[i] = (k < 176) ? f2bf(Wih_d[m * 176 + k]) : (unsigned short)0;
        } else if (idx < 65536 + 98304 + 36864) {
            int i = idx - (65536 + 98304);
            int tap = i >> 12, o = (i >> 6) & 63, c = i & 63;
            WT1bf[i] = f2bf(Wc1[(o * 64 + c) * 9 + tap]);
        } else if (idx < 65536 + 98304 + 36864 + 9216) {
            int i = idx - (65536 + 98304 + 36864);
            int tap = i >> 10, o = (i >> 6) & 15, c = i & 63;
            WT2bf[i] = f2bf(Wc2[(o * 64 + c) * 9 + tap]);
        } else if (idx < PREP_ELEMS) {
            int i = idx - (65536 + 98304 + 36864 + 9216);
            int m = i / 96, k = i % 96;
            Wenc_bf[i] = f2bf((k < 32) ? Wih_e[m * 32 + k] : Whh_e[m * 64 + (k - 32)]);
        }
        return;
    }
    // ---- dedup block ----
    __shared__ unsigned bm[1152];       // 36864 bits
    __shared__ int pcs[1024];
    for (int i = t; i < 1152; i += 1024) bm[i] = 0u;
    __syncthreads();
    for (int i = t; i < 12288; i += 1024) {
        const int r = masks_idxs[i];
        atomicOr(&bm[r >> 5], 1u << (r & 31));
    }
    __syncthreads();
    int pc = 0;
    if (t < 576) pc = __popc(bm[2 * t]) + __popc(bm[2 * t + 1]);
    pcs[t] = pc;
    __syncthreads();
    for (int ofs = 1; ofs < 1024; ofs <<= 1) {
        int v = (t >= ofs) ? pcs[t - ofs] : 0;
        __syncthreads();
        pcs[t] += v;
        __syncthreads();
    }
    if (t == 1023) list_count[0] = pcs[1023];
    if (t < 576) {
        int base = pcs[t] - pc;   // exclusive prefix
#pragma unroll
        for (int wi = 0; wi < 2; ++wi) {
            unsigned wv = bm[2 * t + wi];
            const int rowbase = (2 * t + wi) * 32;
            while (wv) {
                const int bit = __ffs(wv) - 1;
                list[base++] = rowbase + bit;
                wv &= wv - 1;
            }
        }
    }
}

// ---------------------------------------------------------------------------
// Encoder LSTM via MFMA, deduplicated rows (R5/R6 known-best structure).
// ---------------------------------------------------------------------------
__global__ __launch_bounds__(256, 3)
void enc_lstm_kernel(const float* __restrict__ obs_traj,   // [16,192,2]
                     const float* __restrict__ obs_ngbrs,  // [16,36864,2]
                     const float* __restrict__ Wip, const float* __restrict__ bip,
                     const unsigned short* __restrict__ Wenc_bf,  // [256][96]
                     const float* __restrict__ bih, const float* __restrict__ bhh,
                     const int* __restrict__ list, const int* __restrict__ list_count,
                     float* __restrict__ Hn,               // [36864,64] fp32 (sparse rows)
                     float* __restrict__ final_h)          // [192,64] fp32
{
    __shared__ __align__(16) short embs[16 * 16 * 40];   // 20480 B
    __shared__ __align__(16) short hb[2][16 * 72];       // 4608 B
    __shared__ int rows_s[16];

    const int t = threadIdx.x;
    const int wj = t >> 6, lane = t & 63, ln = lane & 15, kq = lane >> 4;
    const int b = blockIdx.x;
    const bool is_ego = (b >= PAIR_GROUPS);

    if (!is_ego) {
        const int cnt = list_count[0];
        if (b * 16 >= cnt) return;                       // uniform exit
        if (t < 16) rows_s[t] = list[min(b * 16 + t, cnt - 1)];
    } else {
        if (t < 16) rows_s[t] = (b - PAIR_GROUPS) * 16 + t;
    }

    // A-frags: A[m][k], m = g*64 + wj*16 + ln, k = kq*8 + j  (b128 loads)
    short8 afrag[4][3];
#pragma unroll
    for (int g = 0; g < 4; ++g)
#pragma unroll
        for (int kc = 0; kc < 3; ++kc)
            afrag[g][kc] = *(const short8*)&Wenc_bf[(g * 64 + wj * 16 + ln) * 96 + kc * 32 + kq * 8];

    float bsv[4][4];
#pragma unroll
    for (int g = 0; g < 4; ++g)
#pragma unroll
        for (int r = 0; r < 4; ++r) {
            const int m = g * 64 + wj * 16 + kq * 4 + r;
            bsv[g][r] = bih[m] + bhh[m];
        }

    __syncthreads();   // rows_s visible

    // emb precompute: one (stp,row) per thread
    {
        const int row = t & 15, stp = t >> 4;
        const int r = rows_s[row];
        const float* sp = is_ego ? (obs_traj + stp * NNODES * 2)
                                 : (obs_ngbrs + stp * PAIRS * 2);
        const float x0 = sp[r * 2 + 0];
        const float x1 = sp[r * 2 + 1];
        unsigned* dst = (unsigned*)&embs[(stp * 16 + row) * 40];
#pragma unroll
        for (int k = 0; k < 32; k += 2) {
            const float e0 = lrelu(fmaf(x0, Wip[2 * k + 0], fmaf(x1, Wip[2 * k + 1], bip[k])));
            const float e1 = lrelu(fmaf(x0, Wip[2 * k + 2], fmaf(x1, Wip[2 * k + 3], bip[k + 1])));
            dst[k >> 1] = (unsigned)f2bf(e0) | ((unsigned)f2bf(e1) << 16);
        }
    }
    for (int i = t; i < 2 * 16 * 72 / 2; i += 256) ((unsigned*)hb)[i] = 0u;
    __syncthreads();

    float cst[4] = {0.f, 0.f, 0.f, 0.f};
    int p = 0;
    for (int stp = 0; stp < OBS_LEN; ++stp) {
        const short8 bf0 = *(const short8*)&embs[(stp * 16 + ln) * 40 + kq * 8];
        const short* hbp = &hb[p][ln * 72 + kq * 8];
        const short8 bf1 = *(const short8*)hbp;
        const short8 bf2 = *(const short8*)(hbp + 32);
        f32x4 acc[4];
#pragma unroll
        for (int g = 0; g < 4; ++g) {
            f32x4 a = { bsv[g][0], bsv[g][1], bsv[g][2], bsv[g][3] };
            a = __builtin_amdgcn_mfma_f32_16x16x32_bf16(afrag[g][0], bf0, a, 0, 0, 0);
            a = __builtin_amdgcn_mfma_f32_16x16x32_bf16(afrag[g][1], bf1, a, 0, 0, 0);
            acc[g] = __builtin_amdgcn_mfma_f32_16x16x32_bf16(afrag[g][2], bf2, a, 0, 0, 0);
        }
        unsigned long long pk = 0;
#pragma unroll
        for (int r = 0; r < 4; ++r) {
            const float cn = fmaf(sigm(acc[1][r]), cst[r], sigm(acc[0][r]) * tanh_f(acc[2][r]));
            cst[r] = cn;
            const float h = sigm(acc[3][r]) * tanh_f(cn);
            pk |= (unsigned long long)f2bf(h) << (16 * r);
        }
        *(unsigned long long*)&hb[1 - p][ln * 72 + wj * 16 + kq * 4] = pk;   // other buffer
        p ^= 1;
        __syncthreads();   // new h visible; old-buffer reads were before writes
    }

    // final h -> global (fp32)
    {
        const int row = t >> 4, k0 = (t & 15) * 4;
        unsigned long long pk = *(const unsigned long long*)&hb[p][row * 72 + k0];
        float4 v;
        v.x = bf2f((unsigned short)(pk));
        v.y = bf2f((unsigned short)(pk >> 16));
        v.z = bf2f((unsigned short)(pk >> 32));
        v.w = bf2f((unsigned short)(pk >> 48));
        float* dst = is_ego ? (final_h + rows_s[row] * 64 + k0)
                            : (Hn + (long)rows_s[row] * 64 + k0);
        *(float4*)dst = v;
    }
}

// ---------------------------------------------------------------------------
// conv via MFMA, NO im2col: social grid stored transposed in2T[p][c] (c
// contiguous) so each tap's B-fragment is a direct ds_read_b128 at shifted p.
// conv1: per wave: M-tile o=[16w,16w+16), 3 N-tiles, 9 taps x 2 K-chunks
//        (18-deep acc chain). A from tap-major WT1bf.
// conv2: s1 stored transposed s1T[n1][o]; 18 (tap,kc) pairs K-split across
//        4 waves + LDS reduce. LDS total ~23 KB (was 94 KB).
// ---------------------------------------------------------------------------
__global__ __launch_bounds__(256, 2)
void conv_kernel(const float* __restrict__ Hn, const int* __restrict__ masks_idxs,
                 const float* __restrict__ final_h, const float* __restrict__ Wdyn,
                 const float* __restrict__ bdyn,
                 const unsigned short* __restrict__ WT1bf, const float* __restrict__ bc1,
                 const unsigned short* __restrict__ WT2bf, const float* __restrict__ bc2,
                 float* __restrict__ enc)
{
    __shared__ __align__(16) short in2T[64][72];    // 9216 B  [p][c]
    __shared__ __align__(16) short s1T[36][72];     // 5184 B  [n1][o]
    __shared__ __align__(16) float red[4][256];     // 4096 B
    __shared__ float s2s[16 * 17];                  // 1088 B

    const int t = threadIdx.x, b = blockIdx.x;
    const int w = t >> 6, lane = t & 63, ln = lane & 15, kq = lane >> 4;

    // conv1 A-frags: a1f[tap][kc], m = w*16+ln (L2 loads, issued early)
    short8 a1f[9][2];
#pragma unroll
    for (int tap = 0; tap < 9; ++tap)
#pragma unroll
        for (int kc = 0; kc < 2; ++kc)
            a1f[tap][kc] = *(const short8*)&WT1bf[(tap * 64 + w * 16 + ln) * 64 + kc * 32 + kq * 8];

    // conv2: wave w owns (tap,kc) pair indices [p2start, p2start+p2cnt) of 18
    const int p2start = (w < 2) ? w * 5 : 10 + (w - 2) * 4;
    const int p2cnt = (w < 2) ? 5 : 4;
    short8 a2f[5];
#pragma unroll
    for (int i = 0; i < 5; ++i) {
        const int pi = p2start + min(i, p2cnt - 1);
        const int tap = pi >> 1, kc = pi & 1;
        a2f[i] = *(const short8*)&WT2bf[(tap * 16 + ln) * 64 + kc * 32 + kq * 8];
    }

    // gather social grid transposed: in2T[p][c] (bf16; lossless re-encode)
    for (int i = 0; i < 16; ++i) {
        const int c = t & 63;
        const int p = (i << 2) + (t >> 6);      // p = u*8 + v
        const int u = p >> 3, v = p & 7;
        const int row = masks_idxs[b * 64 + v * 8 + u];
        in2T[p][c] = (short)f2bf(Hn[(long)row * 64 + c]);
    }
    // traj_enc
    if (t < 32) {
        float acc = bdyn[t];
        for (int k = 0; k < 64; ++k) acc = fmaf(final_h[b * 64 + k], Wdyn[t * 64 + k], acc);
        enc[b * SOCDYN + t] = lrelu(acc);
    }
    __syncthreads();

    // conv1: direct-tap MFMA, 3 N-tiles
    {
        float bcv[4];
#pragma unroll
        for (int r = 0; r < 4; ++r) bcv[r] = bc1[w * 16 + kq * 4 + r];
#pragma unroll
        for (int nt = 0; nt < 3; ++nt) {
            const int n = min(nt * 16 + ln, 35);
            const int x = n / 6, y = n % 6;
            f32x4 acc = { bcv[0], bcv[1], bcv[2], bcv[3] };
#pragma unroll
            for (int tap = 0; tap < 9; ++tap) {
                const int dx = tap / 3, dy = tap % 3;
                const short* bp = &in2T[(x + dx) * 8 + (y + dy)][kq * 8];
#pragma unroll
                for (int kc = 0; kc < 2; ++kc) {
                    const short8 bfr = *(const short8*)(bp + kc * 32);
                    acc = __builtin_amdgcn_mfma_f32_16x16x32_bf16(a1f[tap][kc], bfr, acc, 0, 0, 0);
                }
            }
            if (nt * 16 + ln < 36) {
                unsigned long long pk = 0;
#pragma unroll
                for (int r = 0; r < 4; ++r)
                    pk |= (unsigned long long)f2bf(lrelu(acc[r])) << (16 * r);
                // s1T[n1 = n][o = w*16 + kq*4 + r], 4 consecutive o -> b64
                *(unsigned long long*)&s1T[n][w * 16 + kq * 4] = pk;
            }
        }
    }
    __syncthreads();

    // conv2: direct-tap MFMA, K-split partials
    {
        const int x = ln >> 2, y = ln & 3;     // n2 = ln
        f32x4 acc = { 0.f, 0.f, 0.f, 0.f };
#pragma unroll
        for (int i = 0; i < 5; ++i) {
            if (i < p2cnt) {
                const int pi = p2start + i;
                const int tap = pi >> 1, kc = pi & 1;
                const int dx = tap / 3, dy = tap % 3;
                const short8 bfr = *(const short8*)&s1T[(x + dx) * 6 + (y + dy)][kc * 32 + kq * 8];
                acc = __builtin_amdgcn_mfma_f32_16x16x32_bf16(a2f[i], bfr, acc, 0, 0, 0);
            }
        }
        *(f32x4*)&red[w][lane * 4] = acc;
    }
    __syncthreads();

    // reduce partials + bias + lrelu -> s2s[m][n2]
    {
        const float v = red[0][t] + red[1][t] + red[2][t] + red[3][t];
        const int l = t >> 2, r = t & 3;
        const int m = (l >> 4) * 4 + r, n = l & 15;
        s2s[m * 17 + n] = lrelu(v + bc2[m]);
    }
    __syncthreads();

    // maxpool 2x2 stride 1 -> enc[32..175]
    if (t < 144) {
        const int o = t / 9, ij = t % 9, i = ij / 3, j = ij % 3;
        const float v00 = s2s[o * 17 + i * 4 + j];
        const float v01 = s2s[o * 17 + i * 4 + j + 1];
        const float v10 = s2s[o * 17 + (i + 1) * 4 + j];
        const float v11 = s2s[o * 17 + (i + 1) * 4 + j + 1];
        enc[b * SOCDYN + 32 + t] = fmaxf(fmaxf(v00, v01), fmaxf(v10, v11));
    }
}

// ---------------------------------------------------------------------------
// Decoder LSTM via MFMA, LDS h-history (R6) + prepped bf16 weights +
// split MFMA chain (2+2 independent accumulators instead of 4-deep).
// ---------------------------------------------------------------------------
__global__ __launch_bounds__(512, 1)
void dec_kernel(const float* __restrict__ enc,                // [192,176] fp32
                const unsigned short* __restrict__ Wih_bf,    // [512,192] bf16
                const unsigned short* __restrict__ Whh_bf,    // [512,128] bf16
                const float* __restrict__ bih_d, const float* __restrict__ bhh_d,
                const float* __restrict__ Wop, const float* __restrict__ bop,
                float* __restrict__ out)                      // [25,192,5]
{
    __shared__ __align__(16) short encfr[3072];                // 6144 B
    __shared__ __align__(16) short hist[PRED_LEN * 16 * HSTR]; // 108800 B
    __shared__ float wop_s[5 * 128];                           // 2560 B

    const int t = threadIdx.x;
    const int w = t >> 6, lane = t & 63, ln = lane & 15, kq = lane >> 4;
    const int row0 = blockIdx.x * 16;

    for (int i = t; i < 3072; i += 512) {
        const int n = i / 192, k = i % 192;
        const float v = (k < 176) ? enc[(row0 + n) * SOCDYN + k] : 0.f;
        encfr[(k >> 3) * 128 + n * 8 + (k & 7)] = (short)f2bf(v);
    }
    for (int i = t; i < 640; i += 512) wop_s[i] = Wop[i];

    short8 wfrag[4][4];
#pragma unroll
    for (int g = 0; g < 4; ++g)
#pragma unroll
        for (int kc = 0; kc < 4; ++kc)
            wfrag[g][kc] = *(const short8*)&Whh_bf[(g * 128 + w * 16 + ln) * 128 + kc * 32 + kq * 8];

    f32x4 zin[4];
#pragma unroll
    for (int g = 0; g < 4; ++g)
#pragma unroll
        for (int r = 0; r < 4; ++r) {
            const int m = g * 128 + w * 16 + kq * 4 + r;
            zin[g][r] = bih_d[m] + bhh_d[m];
        }

    __syncthreads();

#pragma unroll
    for (int kc = 0; kc < 6; ++kc) {
        const short8 bfr = *(const short8*)&encfr[(kc * 4 + kq) * 128 + ln * 8];
#pragma unroll
        for (int g = 0; g < 4; ++g) {
            const short8 afr = *(const short8*)&Wih_bf[(g * 128 + w * 16 + ln) * 192 + kc * 32 + kq * 8];
            zin[g] = __builtin_amdgcn_mfma_f32_16x16x32_bf16(afr, bfr, zin[g], 0, 0, 0);
        }
    }

    float c4[4] = {0.f, 0.f, 0.f, 0.f};
    const int hb_wr = ln * HSTR + w * 16 + kq * 4;

    for (int stp = 0; stp < PRED_LEN; ++stp) {
        f32x4 z[4];
#pragma unroll
        for (int g = 0; g < 4; ++g) z[g] = zin[g];
        if (stp > 0) {
            const short* hp = &hist[(stp - 1) * 16 * HSTR + ln * HSTR + kq * 8];
            short8 bh[4];
#pragma unroll
            for (int kc = 0; kc < 4; ++kc)
                bh[kc] = *(const short8*)(hp + kc * 32);
            // split chain: z (kc 0,1) and zb (kc 2,3) independent, then add
            f32x4 zb[4];
#pragma unroll
            for (int g = 0; g < 4; ++g) {
                f32x4 zero = { 0.f, 0.f, 0.f, 0.f };
                z[g] = __builtin_amdgcn_mfma_f32_16x16x32_bf16(wfrag[g][0], bh[0], z[g], 0, 0, 0);
                zb[g] = __builtin_amdgcn_mfma_f32_16x16x32_bf16(wfrag[g][2], bh[2], zero, 0, 0, 0);
                z[g] = __builtin_amdgcn_mfma_f32_16x16x32_bf16(wfrag[g][1], bh[1], z[g], 0, 0, 0);
                zb[g] = __builtin_amdgcn_mfma_f32_16x16x32_bf16(wfrag[g][3], bh[3], zb[g], 0, 0, 0);
            }
#pragma unroll
            for (int g = 0; g < 4; ++g)
#pragma unroll
                for (int r = 0; r < 4; ++r) z[g][r] += zb[g][r];
        }
        unsigned long long pk = 0;
#pragma unroll
        for (int r = 0; r < 4; ++r) {
            const float cn = fmaf(sigm(z[1][r]), c4[r], sigm(z[0][r]) * tanh_f(z[2][r]));
            c4[r] = cn;
            const float h = sigm(z[3][r]) * tanh_f(cn);
            pk |= (unsigned long long)f2bf(h) << (16 * r);
        }
        *(unsigned long long*)&hist[stp * 16 * HSTR + hb_wr] = pk;
        __syncthreads();   // hist[stp] visible for next step
    }

    // epilogue: out = hs @ Wop.T (+ exp/exp/tanh), hs from LDS
    for (int pi = t; pi < PRED_LEN * 16; pi += 512) {
        const int ts = pi >> 4, n = pi & 15;
        const short* hp = &hist[(ts * 16 + n) * HSTR];
        float a0 = bop[0], a1 = bop[1], a2 = bop[2], a3 = bop[3], a4 = bop[4];
#pragma unroll 4
        for (int kb = 0; kb < 16; ++kb) {
            const short8 h8 = *(const short8*)(hp + kb * 8);
#pragma unroll
            for (int q = 0; q < 8; ++q) {
                const float h = bf2f((unsigned short)h8[q]);
                const int k = kb * 8 + q;
                a0 = fmaf(h, wop_s[0 * 128 + k], a0);
                a1 = fmaf(h, wop_s[1 * 128 + k], a1);
                a2 = fmaf(h, wop_s[2 * 128 + k], a2);
                a3 = fmaf(h, wop_s[3 * 128 + k], a3);
                a4 = fmaf(h, wop_s[4 * 128 + k], a4);
            }
        }
        float* op = &out[((long)ts * NNODES + row0 + n) * 5];
        op[0] = a0;
        op[1] = a1;
        op[2] = expf_fast(a2);
        op[3] = expf_fast(a3);
        op[4] = tanh_f(a4);
    }
}

// ---------------------------------------------------------------------------
extern "C" void kernel_launch(void* const* d_in, const int* in_sizes, int n_in,
                              void* d_out, int out_size, void* d_ws, size_t ws_size,
                              hipStream_t stream) {
    const float* obs_traj   = (const float*)d_in[0];
    const float* obs_ngbrs  = (const float*)d_in[1];
    const int*   masks_idxs = (const int*)d_in[3];
    const float* Wip   = (const float*)d_in[7];
    const float* bip   = (const float*)d_in[8];
    const float* Wih_e = (const float*)d_in[9];
    const float* Whh_e = (const float*)d_in[10];
    const float* bih_e = (const float*)d_in[11];
    const float* bhh_e = (const float*)d_in[12];
    const float* Wdyn  = (const float*)d_in[13];
    const float* bdyn  = (const float*)d_in[14];
    const float* Wc1   = (const float*)d_in[15];
    const float* bc1   = (const float*)d_in[16];
    const float* Wc2   = (const float*)d_in[17];
    const float* bc2   = (const float*)d_in[18];
    const float* Wih_d = (const float*)d_in[19];
    const float* Whh_d = (const float*)d_in[20];
    const float* bih_d = (const float*)d_in[21];
    const float* bhh_d = (const float*)d_in[22];
    const float* Wop   = (const float*)d_in[23];
    const float* bop   = (const float*)d_in[24];
    float* out = (float*)d_out;

    float* ws = (float*)d_ws;
    float* Hn      = ws;                       // 2359296 f
    float* final_h = Hn + 2359296;             // 12288 f
    float* encb    = final_h + 12288;          // 33792 f
    unsigned short* Whh_bf  = (unsigned short*)(encb + 33792);  // 65536 us
    unsigned short* Wih_bf  = Whh_bf + 65536;                   // 98304 us
    unsigned short* WT1bf   = Wih_bf + 98304;                   // 36864 us
    unsigned short* WT2bf   = WT1bf + 36864;                    // 9216 us
    unsigned short* Wenc_bf = WT2bf + 9216;                     // 24576 us
    int*   list    = (int*)(Wenc_bf + 24576);  // 36864 i32
    int*   list_count = list + 36864;          // 1 i32

    hipLaunchKernelGGL(prep_dedup_kernel, dim3(230), dim3(1024), 0, stream,
                       Wih_d, Whh_d, Wc1, Wc2, Wih_e, Whh_e, masks_idxs,
                       Whh_bf, Wih_bf, WT1bf, WT2bf, Wenc_bf, list, list_count);
    hipLaunchKernelGGL(enc_lstm_kernel, dim3(PAIR_GROUPS + EGO_GROUPS), dim3(256), 0, stream,
                       obs_traj, obs_ngbrs, Wip, bip, Wenc_bf, bih_e, bhh_e,
                       list, list_count, Hn, final_h);
    hipLaunchKernelGGL(conv_kernel, dim3(NNODES), dim3(256), 0, stream,
                       Hn, masks_idxs, final_h, Wdyn, bdyn, WT1bf, bc1, WT2bf, bc2, encb);
    hipLaunchKernelGGL(dec_kernel, dim3(NNODES / 16), dim3(512), 0, stream,
                       encb, Wih_bf, Whh_bf, bih_d, bhh_d, Wop, bop, out);
}

// Round 9
// 187.672 us; speedup vs baseline: 1.1556x; 1.0141x over previous
//
#include <hip/hip_runtime.h>
#include <hip/hip_bf16.h>

#define OBS_LEN 16
#define PRED_LEN 25
#define NNODES 192
#define PAIRS 36864          // 192*192
#define ENC 64
#define EMB 32
#define DEC 128
#define SOCDYN 176           // 144 + 32
#define PAIR_GROUPS 2304     // 36864/16 worst case
#define EGO_GROUPS 12        // 192/16
#define PREP_ELEMS 234496    // 65536+98304+36864+9216+24576
#define HSTR 136             // dec hist row stride in shorts
#define LOG2E 1.4426950408889634f

typedef short short8 __attribute__((ext_vector_type(8)));
typedef float f32x4 __attribute__((ext_vector_type(4)));

__device__ __forceinline__ float sigm(float x) {
    return __builtin_amdgcn_rcpf(1.f + __builtin_amdgcn_exp2f(-LOG2E * x));
}
__device__ __forceinline__ float tanh_f(float x) {
    return fmaf(-2.f, __builtin_amdgcn_rcpf(1.f + __builtin_amdgcn_exp2f((2.f * LOG2E) * x)), 1.f);
}
__device__ __forceinline__ float expf_fast(float x) {
    return __builtin_amdgcn_exp2f(LOG2E * x);
}
__device__ __forceinline__ float lrelu(float x) { return (x >= 0.f) ? x : 0.1f * x; }

__device__ __forceinline__ unsigned short f2bf(float f) {
    union { float f; unsigned u; } v; v.f = f;
    unsigned r = v.u + 0x7fffu + ((v.u >> 16) & 1u);   // RNE
    return (unsigned short)(r >> 16);
}
__device__ __forceinline__ float bf2f(unsigned short s) {
    union { unsigned u; float f; } v; v.u = ((unsigned)s) << 16; return v.f;
}

// ---------------------------------------------------------------------------
// Kernel 1: prep (blocks 0..228) + dedup of masks_idxs (block 229).
//  Whh_bf [512][128] bf16            (decoder recurrent)
//  Wih_bf [512][192] bf16 K-padded   (decoder input proj)
//  WT1bf  [9 tap][64 o][64 c] bf16   (conv1, tap-major for direct-B conv)
//  WT2bf  [9 tap][16 o][64 c] bf16   (conv2)
//  Wenc_bf[256][96] bf16             (encoder [Wih|Whh] fused)
// ---------------------------------------------------------------------------
__global__ __launch_bounds__(1024, 1)
void prep_dedup_kernel(const float* __restrict__ Wih_d, const float* __restrict__ Whh_d,
                       const float* __restrict__ Wc1, const float* __restrict__ Wc2,
                       const float* __restrict__ Wih_e, const float* __restrict__ Whh_e,
                       const int* __restrict__ masks_idxs,
                       unsigned short* __restrict__ Whh_bf, unsigned short* __restrict__ Wih_bf,
                       unsigned short* __restrict__ WT1bf, unsigned short* __restrict__ WT2bf,
                       unsigned short* __restrict__ Wenc_bf,
                       int* __restrict__ list, int* __restrict__ list_count)
{
    const int t = threadIdx.x, b = blockIdx.x;
    if (b < 229) {
        int idx = b * 1024 + t;
        if (idx < 65536) {
            int m = idx >> 7, k = idx & 127;
            Whh_bf[idx] = f2bf(Whh_d[m * 128 + k]);
        } else if (idx < 65536 + 98304) {
            int i = idx - 65536;
            int m = i / 192, k = i % 192;
            Wih_bf[i] = (k < 176) ? f2bf(Wih_d[m * 176 + k]) : (unsigned short)0;
        } else if (idx < 65536 + 98304 + 36864) {
            int i = idx - (65536 + 98304);
            int tap = i >> 12, o = (i >> 6) & 63, c = i & 63;
            WT1bf[i] = f2bf(Wc1[(o * 64 + c) * 9 + tap]);
        } else if (idx < 65536 + 98304 + 36864 + 9216) {
            int i = idx - (65536 + 98304 + 36864);
            int tap = i >> 10, o = (i >> 6) & 15, c = i & 63;
            WT2bf[i] = f2bf(Wc2[(o * 64 + c) * 9 + tap]);
        } else if (idx < PREP_ELEMS) {
            int i = idx - (65536 + 98304 + 36864 + 9216);
            int m = i / 96, k = i % 96;
            Wenc_bf[i] = f2bf((k < 32) ? Wih_e[m * 32 + k] : Whh_e[m * 64 + (k - 32)]);
        }
        return;
    }
    // ---- dedup block ----
    __shared__ unsigned bm[1152];       // 36864 bits
    __shared__ int pcs[1024];
    for (int i = t; i < 1152; i += 1024) bm[i] = 0u;
    __syncthreads();
    for (int i = t; i < 12288; i += 1024) {
        const int r = masks_idxs[i];
        atomicOr(&bm[r >> 5], 1u << (r & 31));
    }
    __syncthreads();
    int pc = 0;
    if (t < 576) pc = __popc(bm[2 * t]) + __popc(bm[2 * t + 1]);
    pcs[t] = pc;
    __syncthreads();
    for (int ofs = 1; ofs < 1024; ofs <<= 1) {
        int v = (t >= ofs) ? pcs[t - ofs] : 0;
        __syncthreads();
        pcs[t] += v;
        __syncthreads();
    }
    if (t == 1023) list_count[0] = pcs[1023];
    if (t < 576) {
        int base = pcs[t] - pc;   // exclusive prefix
#pragma unroll
        for (int wi = 0; wi < 2; ++wi) {
            unsigned wv = bm[2 * t + wi];
            const int rowbase = (2 * t + wi) * 32;
            while (wv) {
                const int bit = __ffs(wv) - 1;
                list[base++] = rowbase + bit;
                wv &= wv - 1;
            }
        }
    }
}

// ---------------------------------------------------------------------------
// Encoder LSTM via MFMA, deduplicated rows. Hn now stored as bf16 (h is
// bf16-rounded anyway) -> epilogue is a straight LDS->global short8 copy,
// half the scatter bytes (128 B rows = 2 cache lines).
// ---------------------------------------------------------------------------
__global__ __launch_bounds__(256, 3)
void enc_lstm_kernel(const float* __restrict__ obs_traj,   // [16,192,2]
                     const float* __restrict__ obs_ngbrs,  // [16,36864,2]
                     const float* __restrict__ Wip, const float* __restrict__ bip,
                     const unsigned short* __restrict__ Wenc_bf,  // [256][96]
                     const float* __restrict__ bih, const float* __restrict__ bhh,
                     const int* __restrict__ list, const int* __restrict__ list_count,
                     unsigned short* __restrict__ Hn16,    // [36864,64] bf16 (sparse rows)
                     float* __restrict__ final_h)          // [192,64] fp32
{
    __shared__ __align__(16) short embs[16 * 16 * 40];   // 20480 B
    __shared__ __align__(16) short hb[2][16 * 72];       // 4608 B
    __shared__ int rows_s[16];

    const int t = threadIdx.x;
    const int wj = t >> 6, lane = t & 63, ln = lane & 15, kq = lane >> 4;
    const int b = blockIdx.x;
    const bool is_ego = (b >= PAIR_GROUPS);

    if (!is_ego) {
        const int cnt = list_count[0];
        if (b * 16 >= cnt) return;                       // uniform exit
        if (t < 16) rows_s[t] = list[min(b * 16 + t, cnt - 1)];
    } else {
        if (t < 16) rows_s[t] = (b - PAIR_GROUPS) * 16 + t;
    }

    // A-frags: A[m][k], m = g*64 + wj*16 + ln, k = kq*8 + j  (b128 loads)
    short8 afrag[4][3];
#pragma unroll
    for (int g = 0; g < 4; ++g)
#pragma unroll
        for (int kc = 0; kc < 3; ++kc)
            afrag[g][kc] = *(const short8*)&Wenc_bf[(g * 64 + wj * 16 + ln) * 96 + kc * 32 + kq * 8];

    float bsv[4][4];
#pragma unroll
    for (int g = 0; g < 4; ++g)
#pragma unroll
        for (int r = 0; r < 4; ++r) {
            const int m = g * 64 + wj * 16 + kq * 4 + r;
            bsv[g][r] = bih[m] + bhh[m];
        }

    __syncthreads();   // rows_s visible

    // emb precompute: one (stp,row) per thread
    {
        const int row = t & 15, stp = t >> 4;
        const int r = rows_s[row];
        const float* sp = is_ego ? (obs_traj + stp * NNODES * 2)
                                 : (obs_ngbrs + stp * PAIRS * 2);
        const float x0 = sp[r * 2 + 0];
        const float x1 = sp[r * 2 + 1];
        unsigned* dst = (unsigned*)&embs[(stp * 16 + row) * 40];
#pragma unroll
        for (int k = 0; k < 32; k += 2) {
            const float e0 = lrelu(fmaf(x0, Wip[2 * k + 0], fmaf(x1, Wip[2 * k + 1], bip[k])));
            const float e1 = lrelu(fmaf(x0, Wip[2 * k + 2], fmaf(x1, Wip[2 * k + 3], bip[k + 1])));
            dst[k >> 1] = (unsigned)f2bf(e0) | ((unsigned)f2bf(e1) << 16);
        }
    }
    for (int i = t; i < 2 * 16 * 72 / 2; i += 256) ((unsigned*)hb)[i] = 0u;
    __syncthreads();

    float cst[4] = {0.f, 0.f, 0.f, 0.f};
    int p = 0;
    for (int stp = 0; stp < OBS_LEN; ++stp) {
        const short8 bf0 = *(const short8*)&embs[(stp * 16 + ln) * 40 + kq * 8];
        const short* hbp = &hb[p][ln * 72 + kq * 8];
        const short8 bf1 = *(const short8*)hbp;
        const short8 bf2 = *(const short8*)(hbp + 32);
        f32x4 acc[4];
#pragma unroll
        for (int g = 0; g < 4; ++g) {
            f32x4 a = { bsv[g][0], bsv[g][1], bsv[g][2], bsv[g][3] };
            a = __builtin_amdgcn_mfma_f32_16x16x32_bf16(afrag[g][0], bf0, a, 0, 0, 0);
            a = __builtin_amdgcn_mfma_f32_16x16x32_bf16(afrag[g][1], bf1, a, 0, 0, 0);
            acc[g] = __builtin_amdgcn_mfma_f32_16x16x32_bf16(afrag[g][2], bf2, a, 0, 0, 0);
        }
        unsigned long long pk = 0;
#pragma unroll
        for (int r = 0; r < 4; ++r) {
            const float cn = fmaf(sigm(acc[1][r]), cst[r], sigm(acc[0][r]) * tanh_f(acc[2][r]));
            cst[r] = cn;
            const float h = sigm(acc[3][r]) * tanh_f(cn);
            pk |= (unsigned long long)f2bf(h) << (16 * r);
        }
        *(unsigned long long*)&hb[1 - p][ln * 72 + wj * 16 + kq * 4] = pk;   // other buffer
        p ^= 1;
        __syncthreads();   // new h visible; old-buffer reads were before writes
    }

    // final h -> global
    if (is_ego) {
        // ego: fp32 final_h (consumed by fp32 traj_enc dot)
        const int row = t >> 4, k0 = (t & 15) * 4;
        unsigned long long pk = *(const unsigned long long*)&hb[p][row * 72 + k0];
        float4 v;
        v.x = bf2f((unsigned short)(pk));
        v.y = bf2f((unsigned short)(pk >> 16));
        v.z = bf2f((unsigned short)(pk >> 32));
        v.w = bf2f((unsigned short)(pk >> 48));
        *(float4*)(final_h + rows_s[row] * 64 + k0) = v;
    } else if (t < 128) {
        // pairs: bf16 Hn, straight copy (b128 per lane)
        const int row = t >> 3, sh0 = (t & 7) * 8;
        const short8 hv = *(const short8*)&hb[p][row * 72 + sh0];
        *(short8*)&Hn16[(long)rows_s[row] * 64 + sh0] = hv;
    }
}

// ---------------------------------------------------------------------------
// conv via MFMA, NO im2col (R8 structure); gathers bf16 Hn directly (no
// fp32 fetch, no f2bf re-encode).
// ---------------------------------------------------------------------------
__global__ __launch_bounds__(256, 2)
void conv_kernel(const unsigned short* __restrict__ Hn16, const int* __restrict__ masks_idxs,
                 const float* __restrict__ final_h, const float* __restrict__ Wdyn,
                 const float* __restrict__ bdyn,
                 const unsigned short* __restrict__ WT1bf, const float* __restrict__ bc1,
                 const unsigned short* __restrict__ WT2bf, const float* __restrict__ bc2,
                 float* __restrict__ enc)
{
    __shared__ __align__(16) short in2T[64][72];    // 9216 B  [p][c]
    __shared__ __align__(16) short s1T[36][72];     // 5184 B  [n1][o]
    __shared__ __align__(16) float red[4][256];     // 4096 B
    __shared__ float s2s[16 * 17];                  // 1088 B

    const int t = threadIdx.x, b = blockIdx.x;
    const int w = t >> 6, lane = t & 63, ln = lane & 15, kq = lane >> 4;

    // conv1 A-frags: a1f[tap][kc], m = w*16+ln (L2 loads, issued early)
    short8 a1f[9][2];
#pragma unroll
    for (int tap = 0; tap < 9; ++tap)
#pragma unroll
        for (int kc = 0; kc < 2; ++kc)
            a1f[tap][kc] = *(const short8*)&WT1bf[(tap * 64 + w * 16 + ln) * 64 + kc * 32 + kq * 8];

    // conv2: wave w owns (tap,kc) pair indices [p2start, p2start+p2cnt) of 18
    const int p2start = (w < 2) ? w * 5 : 10 + (w - 2) * 4;
    const int p2cnt = (w < 2) ? 5 : 4;
    short8 a2f[5];
#pragma unroll
    for (int i = 0; i < 5; ++i) {
        const int pi = p2start + min(i, p2cnt - 1);
        const int tap = pi >> 1, kc = pi & 1;
        a2f[i] = *(const short8*)&WT2bf[(tap * 16 + ln) * 64 + kc * 32 + kq * 8];
    }

    // gather social grid transposed: in2T[p][c] (bf16 straight copy)
    for (int i = 0; i < 16; ++i) {
        const int c = t & 63;
        const int p = (i << 2) + (t >> 6);      // p = u*8 + v
        const int u = p >> 3, v = p & 7;
        const int row = masks_idxs[b * 64 + v * 8 + u];
        in2T[p][c] = (short)Hn16[(long)row * 64 + c];
    }
    // traj_enc
    if (t < 32) {
        float acc = bdyn[t];
        for (int k = 0; k < 64; ++k) acc = fmaf(final_h[b * 64 + k], Wdyn[t * 64 + k], acc);
        enc[b * SOCDYN + t] = lrelu(acc);
    }
    __syncthreads();

    // conv1: direct-tap MFMA, 3 N-tiles
    {
        float bcv[4];
#pragma unroll
        for (int r = 0; r < 4; ++r) bcv[r] = bc1[w * 16 + kq * 4 + r];
#pragma unroll
        for (int nt = 0; nt < 3; ++nt) {
            const int n = min(nt * 16 + ln, 35);
            const int x = n / 6, y = n % 6;
            f32x4 acc = { bcv[0], bcv[1], bcv[2], bcv[3] };
#pragma unroll
            for (int tap = 0; tap < 9; ++tap) {
                const int dx = tap / 3, dy = tap % 3;
                const short* bp = &in2T[(x + dx) * 8 + (y + dy)][kq * 8];
#pragma unroll
                for (int kc = 0; kc < 2; ++kc) {
                    const short8 bfr = *(const short8*)(bp + kc * 32);
                    acc = __builtin_amdgcn_mfma_f32_16x16x32_bf16(a1f[tap][kc], bfr, acc, 0, 0, 0);
                }
            }
            if (nt * 16 + ln < 36) {
                unsigned long long pk = 0;
#pragma unroll
                for (int r = 0; r < 4; ++r)
                    pk |= (unsigned long long)f2bf(lrelu(acc[r])) << (16 * r);
                *(unsigned long long*)&s1T[n][w * 16 + kq * 4] = pk;
            }
        }
    }
    __syncthreads();

    // conv2: direct-tap MFMA, K-split partials
    {
        const int x = ln >> 2, y = ln & 3;     // n2 = ln
        f32x4 acc = { 0.f, 0.f, 0.f, 0.f };
#pragma unroll
        for (int i = 0; i < 5; ++i) {
            if (i < p2cnt) {
                const int pi = p2start + i;
                const int tap = pi >> 1, kc = pi & 1;
                const int dx = tap / 3, dy = tap % 3;
                const short8 bfr = *(const short8*)&s1T[(x + dx) * 6 + (y + dy)][kc * 32 + kq * 8];
                acc = __builtin_amdgcn_mfma_f32_16x16x32_bf16(a2f[i], bfr, acc, 0, 0, 0);
            }
        }
        *(f32x4*)&red[w][lane * 4] = acc;
    }
    __syncthreads();

    // reduce partials + bias + lrelu -> s2s[m][n2]
    {
        const float v = red[0][t] + red[1][t] + red[2][t] + red[3][t];
        const int l = t >> 2, r = t & 3;
        const int m = (l >> 4) * 4 + r, n = l & 15;
        s2s[m * 17 + n] = lrelu(v + bc2[m]);
    }
    __syncthreads();

    // maxpool 2x2 stride 1 -> enc[32..175]
    if (t < 144) {
        const int o = t / 9, ij = t % 9, i = ij / 3, j = ij % 3;
        const float v00 = s2s[o * 17 + i * 4 + j];
        const float v01 = s2s[o * 17 + i * 4 + j + 1];
        const float v10 = s2s[o * 17 + (i + 1) * 4 + j];
        const float v11 = s2s[o * 17 + (i + 1) * 4 + j + 1];
        enc[b * SOCDYN + 32 + t] = fmaxf(fmaxf(v00, v01), fmaxf(v10, v11));
    }
}

// ---------------------------------------------------------------------------
// Decoder LSTM via MFMA (R8: LDS h-history, prepped bf16 weights, split
// 2+2 MFMA chain).
// ---------------------------------------------------------------------------
__global__ __launch_bounds__(512, 1)
void dec_kernel(const float* __restrict__ enc,                // [192,176] fp32
                const unsigned short* __restrict__ Wih_bf,    // [512,192] bf16
                const unsigned short* __restrict__ Whh_bf,    // [512,128] bf16
                const float* __restrict__ bih_d, const float* __restrict__ bhh_d,
                const float* __restrict__ Wop, const float* __restrict__ bop,
                float* __restrict__ out)                      // [25,192,5]
{
    __shared__ __align__(16) short encfr[3072];                // 6144 B
    __shared__ __align__(16) short hist[PRED_LEN * 16 * HSTR]; // 108800 B
    __shared__ float wop_s[5 * 128];                           // 2560 B

    const int t = threadIdx.x;
    const int w = t >> 6, lane = t & 63, ln = lane & 15, kq = lane >> 4;
    const int row0 = blockIdx.x * 16;

    for (int i = t; i < 3072; i += 512) {
        const int n = i / 192, k = i % 192;
        const float v = (k < 176) ? enc[(row0 + n) * SOCDYN + k] : 0.f;
        encfr[(k >> 3) * 128 + n * 8 + (k & 7)] = (short)f2bf(v);
    }
    for (int i = t; i < 640; i += 512) wop_s[i] = Wop[i];

    short8 wfrag[4][4];
#pragma unroll
    for (int g = 0; g < 4; ++g)
#pragma unroll
        for (int kc = 0; kc < 4; ++kc)
            wfrag[g][kc] = *(const short8*)&Whh_bf[(g * 128 + w * 16 + ln) * 128 + kc * 32 + kq * 8];

    f32x4 zin[4];
#pragma unroll
    for (int g = 0; g < 4; ++g)
#pragma unroll
        for (int r = 0; r < 4; ++r) {
            const int m = g * 128 + w * 16 + kq * 4 + r;
            zin[g][r] = bih_d[m] + bhh_d[m];
        }

    __syncthreads();

#pragma unroll
    for (int kc = 0; kc < 6; ++kc) {
        const short8 bfr = *(const short8*)&encfr[(kc * 4 + kq) * 128 + ln * 8];
#pragma unroll
        for (int g = 0; g < 4; ++g) {
            const short8 afr = *(const short8*)&Wih_bf[(g * 128 + w * 16 + ln) * 192 + kc * 32 + kq * 8];
            zin[g] = __builtin_amdgcn_mfma_f32_16x16x32_bf16(afr, bfr, zin[g], 0, 0, 0);
        }
    }

    float c4[4] = {0.f, 0.f, 0.f, 0.f};
    const int hb_wr = ln * HSTR + w * 16 + kq * 4;

    for (int stp = 0; stp < PRED_LEN; ++stp) {
        f32x4 z[4];
#pragma unroll
        for (int g = 0; g < 4; ++g) z[g] = zin[g];
        if (stp > 0) {
            const short* hp = &hist[(stp - 1) * 16 * HSTR + ln * HSTR + kq * 8];
            short8 bh[4];
#pragma unroll
            for (int kc = 0; kc < 4; ++kc)
                bh[kc] = *(const short8*)(hp + kc * 32);
            f32x4 zb[4];
#pragma unroll
            for (int g = 0; g < 4; ++g) {
                f32x4 zero = { 0.f, 0.f, 0.f, 0.f };
                z[g] = __builtin_amdgcn_mfma_f32_16x16x32_bf16(wfrag[g][0], bh[0], z[g], 0, 0, 0);
                zb[g] = __builtin_amdgcn_mfma_f32_16x16x32_bf16(wfrag[g][2], bh[2], zero, 0, 0, 0);
                z[g] = __builtin_amdgcn_mfma_f32_16x16x32_bf16(wfrag[g][1], bh[1], z[g], 0, 0, 0);
                zb[g] = __builtin_amdgcn_mfma_f32_16x16x32_bf16(wfrag[g][3], bh[3], zb[g], 0, 0, 0);
            }
#pragma unroll
            for (int g = 0; g < 4; ++g)
#pragma unroll
                for (int r = 0; r < 4; ++r) z[g][r] += zb[g][r];
        }
        unsigned long long pk = 0;
#pragma unroll
        for (int r = 0; r < 4; ++r) {
            const float cn = fmaf(sigm(z[1][r]), c4[r], sigm(z[0][r]) * tanh_f(z[2][r]));
            c4[r] = cn;
            const float h = sigm(z[3][r]) * tanh_f(cn);
            pk |= (unsigned long long)f2bf(h) << (16 * r);
        }
        *(unsigned long long*)&hist[stp * 16 * HSTR + hb_wr] = pk;
        __syncthreads();   // hist[stp] visible for next step
    }

    // epilogue: out = hs @ Wop.T (+ exp/exp/tanh), hs from LDS
    for (int pi = t; pi < PRED_LEN * 16; pi += 512) {
        const int ts = pi >> 4, n = pi & 15;
        const short* hp = &hist[(ts * 16 + n) * HSTR];
        float a0 = bop[0], a1 = bop[1], a2 = bop[2], a3 = bop[3], a4 = bop[4];
#pragma unroll 4
        for (int kb = 0; kb < 16; ++kb) {
            const short8 h8 = *(const short8*)(hp + kb * 8);
#pragma unroll
            for (int q = 0; q < 8; ++q) {
                const float h = bf2f((unsigned short)h8[q]);
                const int k = kb * 8 + q;
                a0 = fmaf(h, wop_s[0 * 128 + k], a0);
                a1 = fmaf(h, wop_s[1 * 128 + k], a1);
                a2 = fmaf(h, wop_s[2 * 128 + k], a2);
                a3 = fmaf(h, wop_s[3 * 128 + k], a3);
                a4 = fmaf(h, wop_s[4 * 128 + k], a4);
            }
        }
        float* op = &out[((long)ts * NNODES + row0 + n) * 5];
        op[0] = a0;
        op[1] = a1;
        op[2] = expf_fast(a2);
        op[3] = expf_fast(a3);
        op[4] = tanh_f(a4);
    }
}

// ---------------------------------------------------------------------------
extern "C" void kernel_launch(void* const* d_in, const int* in_sizes, int n_in,
                              void* d_out, int out_size, void* d_ws, size_t ws_size,
                              hipStream_t stream) {
    const float* obs_traj   = (const float*)d_in[0];
    const float* obs_ngbrs  = (const float*)d_in[1];
    const int*   masks_idxs = (const int*)d_in[3];
    const float* Wip   = (const float*)d_in[7];
    const float* bip   = (const float*)d_in[8];
    const float* Wih_e = (const float*)d_in[9];
    const float* Whh_e = (const float*)d_in[10];
    const float* bih_e = (const float*)d_in[11];
    const float* bhh_e = (const float*)d_in[12];
    const float* Wdyn  = (const float*)d_in[13];
    const float* bdyn  = (const float*)d_in[14];
    const float* Wc1   = (const float*)d_in[15];
    const float* bc1   = (const float*)d_in[16];
    const float* Wc2   = (const float*)d_in[17];
    const float* bc2   = (const float*)d_in[18];
    const float* Wih_d = (const float*)d_in[19];
    const float* Whh_d = (const float*)d_in[20];
    const float* bih_d = (const float*)d_in[21];
    const float* bhh_d = (const float*)d_in[22];
    const float* Wop   = (const float*)d_in[23];
    const float* bop   = (const float*)d_in[24];
    float* out = (float*)d_out;

    float* ws = (float*)d_ws;
    unsigned short* Hn16 = (unsigned short*)ws;             // 2359296 us (uses half the old Hn region)
    float* final_h = ws + 2359296;             // 12288 f
    float* encb    = final_h + 12288;          // 33792 f
    unsigned short* Whh_bf  = (unsigned short*)(encb + 33792);  // 65536 us
    unsigned short* Wih_bf  = Whh_bf + 65536;                   // 98304 us
    unsigned short* WT1bf   = Wih_bf + 98304;                   // 36864 us
    unsigned short* WT2bf   = WT1bf + 36864;                    // 9216 us
    unsigned short* Wenc_bf = WT2bf + 9216;                     // 24576 us
    int*   list    = (int*)(Wenc_bf + 24576);  // 36864 i32
    int*   list_count = list + 36864;          // 1 i32

    hipLaunchKernelGGL(prep_dedup_kernel, dim3(230), dim3(1024), 0, stream,
                       Wih_d, Whh_d, Wc1, Wc2, Wih_e, Whh_e, masks_idxs,
                       Whh_bf, Wih_bf, WT1bf, WT2bf, Wenc_bf, list, list_count);
    hipLaunchKernelGGL(enc_lstm_kernel, dim3(PAIR_GROUPS + EGO_GROUPS), dim3(256), 0, stream,
                       obs_traj, obs_ngbrs, Wip, bip, Wenc_bf, bih_e, bhh_e,
                       list, list_count, Hn16, final_h);
    hipLaunchKernelGGL(conv_kernel, dim3(NNODES), dim3(256), 0, stream,
                       Hn16, masks_idxs, final_h, Wdyn, bdyn, WT1bf, bc1, WT2bf, bc2, encb);
    hipLaunchKernelGGL(dec_kernel, dim3(NNODES / 16), dim3(512), 0, stream,
                       encb, Wih_bf, Whh_bf, bih_d, bhh_d, Wop, bop, out);
}